// Round 17
// baseline (256.260 us; speedup 1.0000x reference)
//
#include <hip/hip_runtime.h>
#include <hip/hip_bf16.h>
#include <math.h>

typedef __attribute__((ext_vector_type(8))) short bf16x8;
typedef __attribute__((ext_vector_type(16))) float f32x16;

#define B_ 32
#define C_ 256
#define K_ 2048
#define HW_ 784
#define NPIX 25088
#define FEAT_BSTRIDE 230400
#define FEAT_CSTRIDE 900
#define INV_DELTA 15.0f
#define LOG2E 1.4426950408889634f
#define QSCALE 409.6f
#define QDEC (LOG2E / QSCALE)

#define BM 128
#define BN 128
#define BKC 32
#define NCH 8
#define NSLAB 16

#define AS1 __attribute__((address_space(1)))
#define AS3 __attribute__((address_space(3)))

__device__ __forceinline__ ushort f2bf(float x) {
    __hip_bfloat16 h = __float2bfloat16(x);
    return *reinterpret_cast<ushort*>(&h);
}
__device__ __forceinline__ float bf2f(ushort u) {
    __hip_bfloat16 h;
    *reinterpret_cast<ushort*>(&h) = u;
    return __bfloat162float(h);
}
__device__ __forceinline__ void gl_lds16(const ushort* g, ushort* l) {
    __builtin_amdgcn_global_load_lds((AS1 const uint*)g, (AS3 uint*)l, 16, 0, 0);
}

// ---------------- split embedding into bf16 hi/lo + e2 (fused, one emb read) ----------------
__global__ __launch_bounds__(256) void prep_e_kernel(const float* __restrict__ emb,
                                                     ushort* __restrict__ ehi,
                                                     ushort* __restrict__ elo,
                                                     float* __restrict__ e2) {
    __shared__ float ws[4];
    int k = blockIdx.x, t = threadIdx.x;          // one k-row per block
    int i = k * C_ + t;
    float v = emb[i];
    ushort h = f2bf(v);
    float r = v - bf2f(h);
    ehi[i] = h;
    elo[i] = f2bf(r);
    float s = v * v;
#pragma unroll
    for (int off = 32; off > 0; off >>= 1) s += __shfl_xor(s, off);
    if ((t & 63) == 0) ws[t >> 6] = s;
    __syncthreads();
    if (t == 0) e2[k] = ws[0] + ws[1] + ws[2] + ws[3];
}

// ---------------- crop + transpose + split features into bf16 hi/lo [px][c] ----------------
__global__ __launch_bounds__(256) void prep_f_kernel(const float* __restrict__ feat,
                                                     ushort* __restrict__ fhi,
                                                     ushort* __restrict__ flo) {
    __shared__ float F[256 * 65];
    int t = threadIdx.x;
    int px0 = blockIdx.x * 64;
    {
        int lane = t & 63, cq = t >> 6;
        int px = px0 + lane;
        int b = px / HW_, hw = px % HW_;
        int h = hw / 28, w = hw % 28;
        const float* base = feat + (size_t)b * FEAT_BSTRIDE + (size_t)(h + 1) * 30 + (w + 1);
#pragma unroll
        for (int cc = 0; cc < 64; ++cc) {
            int c = cq * 64 + cc;
            F[c * 65 + lane] = base[(size_t)c * FEAT_CSTRIDE];
        }
    }
    __syncthreads();
    {
        int px_l = t >> 2, cseg = t & 3;
        size_t ob = (size_t)(px0 + px_l) * C_ + cseg * 64;
        uint uh[32], ul[32];
#pragma unroll
        for (int j = 0; j < 32; ++j) {
            float v0 = F[(cseg * 64 + 2 * j) * 65 + px_l];
            float v1 = F[(cseg * 64 + 2 * j + 1) * 65 + px_l];
            ushort h0 = f2bf(v0), h1 = f2bf(v1);
            float r0 = v0 - bf2f(h0), r1 = v1 - bf2f(h1);
            uh[j] = (uint)h0 | ((uint)h1 << 16);
            ul[j] = (uint)f2bf(r0) | ((uint)f2bf(r1) << 16);
        }
#pragma unroll
        for (int j = 0; j < 8; ++j) {
            *reinterpret_cast<uint4*>(&fhi[ob + j * 8]) = *reinterpret_cast<uint4*>(&uh[j * 4]);
            *reinterpret_cast<uint4*>(&flo[ob + j * 8]) = *reinterpret_cast<uint4*>(&ul[j * 4]);
        }
    }
}

// ---------------- MFMA GEMM (R14, byte-identical): swapped operands D[k][px] ----------------
__global__ __launch_bounds__(256, 3) void gemm_kernel(
    const ushort* __restrict__ fhi, const ushort* __restrict__ flo,
    const ushort* __restrict__ ehi, const ushort* __restrict__ elo,
    const float* __restrict__ mdm, const float* __restrict__ e2g,
    ushort* __restrict__ zq, float* __restrict__ m_part, float* __restrict__ l_part)
{
    __shared__ __align__(16) ushort Fsmem[2][2][BM * BKC];  // [dbuf][hi/lo][8KB] = 32 KB
    __shared__ float redA[2][132];
    __shared__ float redM[132];

    int t = threadIdx.x;
    int lane = t & 63, wid = t >> 6;
    int wrow = wid >> 1, wcol = wid & 1;
    int g = lane >> 5, ci = lane & 31;

    int bid = blockIdx.x;
    int swz = (bid & 7) * 392 + (bid >> 3);
    int tile = swz >> 4, slab = swz & 15;
    int px0 = tile * BM;
    int k0 = slab * BN;

    auto stageF = [&](int buf, int ch) {
        int c0 = ch * BKC;
#pragma unroll
        for (int i = 0; i < 2; ++i) {
            int p = t + i * 256;
            int rp = p >> 3, q = p & 7;
            int v = q ^ (rp & 7);
            int row = rp * 2 + (v >> 2);
            int cu = (v & 3) * 8;
            size_t ga = (size_t)(px0 + row) * C_ + c0 + cu;
            gl_lds16(fhi + ga, &Fsmem[buf][0][p * 8]);
            gl_lds16(flo + ga, &Fsmem[buf][1][p * 8]);
        }
    };

    const ushort* peh[2];
    const ushort* pel[2];
#pragma unroll
    for (int ni = 0; ni < 2; ++ni) {
        size_t r = (size_t)(k0 + wcol * 64 + ni * 32 + ci) * C_ + g * 8;
        peh[ni] = ehi + r;
        pel[ni] = elo + r;
    }
    bf16x8 ehS[2][2], elS[2][2];
    auto loadE = [&](int slot, int gs) {
        int off = gs * 16;
#pragma unroll
        for (int ni = 0; ni < 2; ++ni) {
            ehS[slot][ni] = *reinterpret_cast<const bf16x8*>(peh[ni] + off);
            elS[slot][ni] = *reinterpret_cast<const bf16x8*>(pel[ni] + off);
        }
    };

    f32x16 acc[2][2];
#pragma unroll
    for (int mi = 0; mi < 2; ++mi)
#pragma unroll
        for (int ni = 0; ni < 2; ++ni)
            acc[mi][ni] = (f32x16)(0.0f);

    int xr = (ci >> 1) & 7;
    int bb4 = (ci & 1) * 4;
    int rpF0 = wrow * 32 + (ci >> 1);

    stageF(0, 0);
    loadE(0, 0);
    asm volatile("s_waitcnt vmcnt(2)" ::: "memory");
    __builtin_amdgcn_s_barrier();

#pragma unroll
    for (int ch = 0; ch < NCH; ++ch) {
        if (ch + 1 < NCH) stageF((ch + 1) & 1, ch + 1);
#pragma unroll
        for (int s = 0; s < 2; ++s) {
            int gs = ch * 2 + s;
            if (gs + 1 < 2 * NCH) loadE((gs + 1) & 1, gs + 1);
            __builtin_amdgcn_sched_barrier(0);
            int qs = (bb4 + s * 2 + g) ^ xr;
            bf16x8 fh[2], fl[2];
#pragma unroll
            for (int mi = 0; mi < 2; ++mi) {
                int off = (rpF0 + mi * 16) * 64 + qs * 8;
                fh[mi] = *reinterpret_cast<const bf16x8*>(&Fsmem[ch & 1][0][off]);
                fl[mi] = *reinterpret_cast<const bf16x8*>(&Fsmem[ch & 1][1][off]);
            }
            int cs = gs & 1;
#pragma unroll
            for (int mi = 0; mi < 2; ++mi)
#pragma unroll
                for (int ni = 0; ni < 2; ++ni) {
                    acc[mi][ni] = __builtin_amdgcn_mfma_f32_32x32x16_bf16(ehS[cs][ni], fh[mi], acc[mi][ni], 0, 0, 0);
                    acc[mi][ni] = __builtin_amdgcn_mfma_f32_32x32x16_bf16(elS[cs][ni], fh[mi], acc[mi][ni], 0, 0, 0);
                    acc[mi][ni] = __builtin_amdgcn_mfma_f32_32x32x16_bf16(ehS[cs][ni], fl[mi], acc[mi][ni], 0, 0, 0);
                }
        }
        if (ch + 1 < NCH) {
            asm volatile("s_waitcnt vmcnt(4)" ::: "memory");
            __builtin_amdgcn_s_barrier();
        }
    }

    // ---------------- epilogue (lane-local k) ----------------
    const float alpha = INV_DELTA / mdm[0];
    {
        const float* e2b = e2g + k0 + wcol * 64 + 4 * g;
#pragma unroll
        for (int ni = 0; ni < 2; ++ni)
#pragma unroll
            for (int q = 0; q < 4; ++q) {
                float4 ev = *reinterpret_cast<const float4*>(e2b + ni * 32 + 8 * q);
#pragma unroll
                for (int mi = 0; mi < 2; ++mi) {
                    acc[mi][ni][4 * q + 0] = alpha * (2.f * acc[mi][ni][4 * q + 0] - ev.x);
                    acc[mi][ni][4 * q + 1] = alpha * (2.f * acc[mi][ni][4 * q + 1] - ev.y);
                    acc[mi][ni][4 * q + 2] = alpha * (2.f * acc[mi][ni][4 * q + 2] - ev.z);
                    acc[mi][ni][4 * q + 3] = alpha * (2.f * acc[mi][ni][4 * q + 3] - ev.w);
                }
            }
    }

    float mt[2];
#pragma unroll
    for (int mi = 0; mi < 2; ++mi) {
        float m = acc[mi][0][0];
#pragma unroll
        for (int ni = 0; ni < 2; ++ni)
#pragma unroll
            for (int r = 0; r < 16; ++r) m = fmaxf(m, acc[mi][ni][r]);
        m = fmaxf(m, __shfl_xor(m, 32));
        mt[mi] = m;
        if (lane < 32) redA[wcol][wrow * 64 + mi * 32 + ci] = m;
    }
    __syncthreads();
    if (t < 128) redM[t] = fmaxf(redA[0][t], redA[1][t]);
    __syncthreads();
    float ms[2];
#pragma unroll
    for (int mi = 0; mi < 2; ++mi) ms[mi] = redM[wrow * 64 + mi * 32 + ci];

#pragma unroll
    for (int mi = 0; mi < 2; ++mi) {
        float l = 0.f;
#pragma unroll
        for (int ni = 0; ni < 2; ++ni)
#pragma unroll
            for (int r = 0; r < 16; ++r) l += exp2f((acc[mi][ni][r] - ms[mi]) * LOG2E);
        l += __shfl_xor(l, 32);
        if (lane < 32) redA[wcol][wrow * 64 + mi * 32 + ci] = l;
    }
    __syncthreads();
    if (t < 128) {
        m_part[(size_t)slab * NPIX + px0 + t] = redM[t];
        l_part[(size_t)slab * NPIX + px0 + t] = redA[0][t] + redA[1][t];
    }

#pragma unroll
    for (int mi = 0; mi < 2; ++mi) {
        int pxx = px0 + wrow * 64 + mi * 32 + ci;
        int bb = pxx / HW_, hh = pxx - bb * HW_;
        ushort* zb = zq + ((size_t)bb * K_ + (k0 + wcol * 64 + 4 * g)) * HW_ + hh;
#pragma unroll
        for (int ni = 0; ni < 2; ++ni)
#pragma unroll
            for (int q = 0; q < 4; ++q)
#pragma unroll
                for (int j = 0; j < 4; ++j) {
                    float s0 = fmaxf((acc[mi][ni][4 * q + j] - ms[mi]) * QSCALE, -32760.f);
                    short v = (short)(int)s0;
                    zb[(size_t)(ni * 32 + 8 * q + j) * HW_] = (ushort)v;
                }
    }
}

// ---------------- combine 16 slab partials ----------------
__global__ void combine_kernel(const float* __restrict__ m_part, const float* __restrict__ l_part,
                               float* __restrict__ m_fin, float* __restrict__ rl_g) {
    int p = blockIdx.x * 256 + threadIdx.x;
    float m = -3.4e38f;
#pragma unroll
    for (int s = 0; s < NSLAB; ++s) m = fmaxf(m, m_part[(size_t)s * NPIX + p]);
    float l = 0.f;
#pragma unroll
    for (int s = 0; s < NSLAB; ++s)
        l += l_part[(size_t)s * NPIX + p] * exp2f((m_part[(size_t)s * NPIX + p] - m) * LOG2E);
    m_fin[p] = m;
    rl_g[p] = 1.0f / l;
}

// ---------------- finish: slab-sized blocks (128 k), corr staged once ----------------
__global__ __launch_bounds__(256) void finish_kernel(
    const ushort* __restrict__ zq, const float* __restrict__ m_part,
    const float* __restrict__ m_fin, const float* __restrict__ rl_g,
    float* __restrict__ codes, float* __restrict__ bow)
{
    __shared__ float corr[HW_], rls[HW_];
    __shared__ float bsum[128][4];
    int t = threadIdx.x;
    int slab = blockIdx.x, b = blockIdx.y;
    for (int i = t; i < HW_; i += 256) {
        int p = b * HW_ + i;
        corr[i] = (m_part[(size_t)slab * NPIX + p] - m_fin[p]) * LOG2E;
        rls[i] = rl_g[p];
    }
    __syncthreads();
    int wid = t >> 6, lane = t & 63;
    for (int kl = 0; kl < 128; ++kl) {
        int k = slab * 128 + kl;
        size_t base = ((size_t)b * K_ + k) * HW_;
        float ssum = 0.f;
        if (t < 196) {
            uint2 raw = *reinterpret_cast<const uint2*>(&zq[base + t * 4]);
            int q0 = (int)(short)(raw.x & 0xffffu), q1 = (int)(short)(raw.x >> 16);
            int q2 = (int)(short)(raw.y & 0xffffu), q3 = (int)(short)(raw.y >> 16);
            float4 out;
            out.x = exp2f(fmaf((float)q0, QDEC, corr[t * 4 + 0])) * rls[t * 4 + 0];
            out.y = exp2f(fmaf((float)q1, QDEC, corr[t * 4 + 1])) * rls[t * 4 + 1];
            out.z = exp2f(fmaf((float)q2, QDEC, corr[t * 4 + 2])) * rls[t * 4 + 2];
            out.w = exp2f(fmaf((float)q3, QDEC, corr[t * 4 + 3])) * rls[t * 4 + 3];
            *reinterpret_cast<float4*>(&codes[base + t * 4]) = out;
            ssum = out.x + out.y + out.z + out.w;
        }
#pragma unroll
        for (int off = 32; off > 0; off >>= 1) ssum += __shfl_xor(ssum, off);
        if (lane == 0) bsum[kl][wid] = ssum;
    }
    __syncthreads();
    if (t < 128) {
        float s = bsum[t][0] + bsum[t][1] + bsum[t][2] + bsum[t][3];
        bow[(size_t)b * K_ + slab * 128 + t] = s * (1.0f / 784.0f);
    }
}

// ---------------- bow row normalize ----------------
__global__ void bownorm_kernel(float* __restrict__ bow) {
    __shared__ float wred[4];
    __shared__ float denom_s;
    int b = blockIdx.x, t = threadIdx.x;
    float* row = bow + (size_t)b * K_;
    float v[8];
    float s = 0.f;
#pragma unroll
    for (int i = 0; i < 8; ++i) {
        v[i] = row[t + i * 256];
        s += fabsf(v[i]);
    }
#pragma unroll
    for (int off = 32; off > 0; off >>= 1) s += __shfl_xor(s, off);
    int wid = t >> 6, lane = t & 63;
    if (lane == 0) wred[wid] = s;
    __syncthreads();
    if (t == 0) denom_s = fmaxf(wred[0] + wred[1] + wred[2] + wred[3], 1e-12f);
    __syncthreads();
    float denom = denom_s;
#pragma unroll
    for (int i = 0; i < 8; ++i) row[t + i * 256] = v[i] / denom;
}

extern "C" void kernel_launch(void* const* d_in, const int* in_sizes, int n_in,
                              void* d_out, int out_size, void* d_ws, size_t ws_size,
                              hipStream_t stream) {
    const float* feat = (const float*)d_in[0];
    const float* emb  = (const float*)d_in[1];
    const float* mdm  = (const float*)d_in[2];
    float* bow   = (float*)d_out;
    float* codes = bow + (size_t)B_ * K_;

    char* ws = (char*)d_ws;
    size_t off = 0;
    auto alloc = [&](size_t bytes) { char* p = ws + off; off = (off + bytes + 255) & ~(size_t)255; return p; };
    ushort* ehi    = (ushort*)alloc((size_t)K_ * C_ * 2);
    ushort* elo    = (ushort*)alloc((size_t)K_ * C_ * 2);
    float*  e2     = (float*)alloc(K_ * 4);
    float*  m_part = (float*)alloc((size_t)NSLAB * NPIX * 4);
    float*  l_part = (float*)alloc((size_t)NSLAB * NPIX * 4);
    float*  m_fin  = (float*)alloc((size_t)NPIX * 4);
    float*  rl_g   = (float*)alloc((size_t)NPIX * 4);
    ushort* zq     = (ushort*)alloc((size_t)NPIX * K_ * 2);

    // fhi/flo live in the codes output region: dead until finish_kernel (stream-ordered).
    ushort* fhi = (ushort*)codes;
    ushort* flo = fhi + (size_t)NPIX * C_;

    prep_e_kernel<<<2048, 256, 0, stream>>>(emb, ehi, elo, e2);
    prep_f_kernel<<<392, 256, 0, stream>>>(feat, fhi, flo);
    gemm_kernel<<<3136, 256, 0, stream>>>(fhi, flo, ehi, elo, mdm, e2, zq, m_part, l_part);
    combine_kernel<<<98, 256, 0, stream>>>(m_part, l_part, m_fin, rl_g);
    finish_kernel<<<dim3(16, 32), 256, 0, stream>>>(zq, m_part, m_fin, rl_g, codes, bow);
    bownorm_kernel<<<32, 256, 0, stream>>>(bow);
}

// Round 18
// 218.092 us; speedup vs baseline: 1.1750x; 1.1750x over previous
//
#include <hip/hip_runtime.h>
#include <hip/hip_bf16.h>
#include <math.h>

typedef __attribute__((ext_vector_type(8))) short bf16x8;
typedef __attribute__((ext_vector_type(16))) float f32x16;

#define B_ 32
#define C_ 256
#define K_ 2048
#define HW_ 784
#define NPIX 25088
#define FEAT_BSTRIDE 230400
#define FEAT_CSTRIDE 900
#define INV_DELTA 15.0f
#define LOG2E 1.4426950408889634f
#define QSCALE 409.6f
#define QDEC (LOG2E / QSCALE)

#define BM 128
#define BN 128
#define BKC 32
#define NCH 8
#define NSLAB 16

#define AS1 __attribute__((address_space(1)))
#define AS3 __attribute__((address_space(3)))

__device__ __forceinline__ ushort f2bf(float x) {
    __hip_bfloat16 h = __float2bfloat16(x);
    return *reinterpret_cast<ushort*>(&h);
}
__device__ __forceinline__ float bf2f(ushort u) {
    __hip_bfloat16 h;
    *reinterpret_cast<ushort*>(&h) = u;
    return __bfloat162float(h);
}
__device__ __forceinline__ void gl_lds16(const ushort* g, ushort* l) {
    __builtin_amdgcn_global_load_lds((AS1 const uint*)g, (AS3 uint*)l, 16, 0, 0);
}

// ---------------- split embedding into bf16 hi/lo + e2 (fused, one emb read) ----------------
__global__ __launch_bounds__(256) void prep_e_kernel(const float* __restrict__ emb,
                                                     ushort* __restrict__ ehi,
                                                     ushort* __restrict__ elo,
                                                     float* __restrict__ e2) {
    __shared__ float ws[4];
    int k = blockIdx.x, t = threadIdx.x;          // one k-row per block
    int i = k * C_ + t;
    float v = emb[i];
    ushort h = f2bf(v);
    float r = v - bf2f(h);
    ehi[i] = h;
    elo[i] = f2bf(r);
    float s = v * v;
#pragma unroll
    for (int off = 32; off > 0; off >>= 1) s += __shfl_xor(s, off);
    if ((t & 63) == 0) ws[t >> 6] = s;
    __syncthreads();
    if (t == 0) e2[k] = ws[0] + ws[1] + ws[2] + ws[3];
}

// ---------------- crop + transpose + split features into bf16 hi/lo [px][c] ----------------
__global__ __launch_bounds__(256) void prep_f_kernel(const float* __restrict__ feat,
                                                     ushort* __restrict__ fhi,
                                                     ushort* __restrict__ flo) {
    __shared__ float F[256 * 65];
    int t = threadIdx.x;
    int px0 = blockIdx.x * 64;
    {
        int lane = t & 63, cq = t >> 6;
        int px = px0 + lane;
        int b = px / HW_, hw = px % HW_;
        int h = hw / 28, w = hw % 28;
        const float* base = feat + (size_t)b * FEAT_BSTRIDE + (size_t)(h + 1) * 30 + (w + 1);
#pragma unroll
        for (int cc = 0; cc < 64; ++cc) {
            int c = cq * 64 + cc;
            F[c * 65 + lane] = base[(size_t)c * FEAT_CSTRIDE];
        }
    }
    __syncthreads();
    {
        int px_l = t >> 2, cseg = t & 3;
        size_t ob = (size_t)(px0 + px_l) * C_ + cseg * 64;
        uint uh[32], ul[32];
#pragma unroll
        for (int j = 0; j < 32; ++j) {
            float v0 = F[(cseg * 64 + 2 * j) * 65 + px_l];
            float v1 = F[(cseg * 64 + 2 * j + 1) * 65 + px_l];
            ushort h0 = f2bf(v0), h1 = f2bf(v1);
            float r0 = v0 - bf2f(h0), r1 = v1 - bf2f(h1);
            uh[j] = (uint)h0 | ((uint)h1 << 16);
            ul[j] = (uint)f2bf(r0) | ((uint)f2bf(r1) << 16);
        }
#pragma unroll
        for (int j = 0; j < 8; ++j) {
            *reinterpret_cast<uint4*>(&fhi[ob + j * 8]) = *reinterpret_cast<uint4*>(&uh[j * 4]);
            *reinterpret_cast<uint4*>(&flo[ob + j * 8]) = *reinterpret_cast<uint4*>(&ul[j * 4]);
        }
    }
}

// ---------------- MFMA GEMM (R14, byte-identical): swapped operands D[k][px] ----------------
__global__ __launch_bounds__(256, 3) void gemm_kernel(
    const ushort* __restrict__ fhi, const ushort* __restrict__ flo,
    const ushort* __restrict__ ehi, const ushort* __restrict__ elo,
    const float* __restrict__ mdm, const float* __restrict__ e2g,
    ushort* __restrict__ zq, float* __restrict__ m_part, float* __restrict__ l_part)
{
    __shared__ __align__(16) ushort Fsmem[2][2][BM * BKC];  // [dbuf][hi/lo][8KB] = 32 KB
    __shared__ float redA[2][132];
    __shared__ float redM[132];

    int t = threadIdx.x;
    int lane = t & 63, wid = t >> 6;
    int wrow = wid >> 1, wcol = wid & 1;
    int g = lane >> 5, ci = lane & 31;

    int bid = blockIdx.x;
    int swz = (bid & 7) * 392 + (bid >> 3);
    int tile = swz >> 4, slab = swz & 15;
    int px0 = tile * BM;
    int k0 = slab * BN;

    auto stageF = [&](int buf, int ch) {
        int c0 = ch * BKC;
#pragma unroll
        for (int i = 0; i < 2; ++i) {
            int p = t + i * 256;
            int rp = p >> 3, q = p & 7;
            int v = q ^ (rp & 7);
            int row = rp * 2 + (v >> 2);
            int cu = (v & 3) * 8;
            size_t ga = (size_t)(px0 + row) * C_ + c0 + cu;
            gl_lds16(fhi + ga, &Fsmem[buf][0][p * 8]);
            gl_lds16(flo + ga, &Fsmem[buf][1][p * 8]);
        }
    };

    const ushort* peh[2];
    const ushort* pel[2];
#pragma unroll
    for (int ni = 0; ni < 2; ++ni) {
        size_t r = (size_t)(k0 + wcol * 64 + ni * 32 + ci) * C_ + g * 8;
        peh[ni] = ehi + r;
        pel[ni] = elo + r;
    }
    bf16x8 ehS[2][2], elS[2][2];
    auto loadE = [&](int slot, int gs) {
        int off = gs * 16;
#pragma unroll
        for (int ni = 0; ni < 2; ++ni) {
            ehS[slot][ni] = *reinterpret_cast<const bf16x8*>(peh[ni] + off);
            elS[slot][ni] = *reinterpret_cast<const bf16x8*>(pel[ni] + off);
        }
    };

    f32x16 acc[2][2];
#pragma unroll
    for (int mi = 0; mi < 2; ++mi)
#pragma unroll
        for (int ni = 0; ni < 2; ++ni)
            acc[mi][ni] = (f32x16)(0.0f);

    int xr = (ci >> 1) & 7;
    int bb4 = (ci & 1) * 4;
    int rpF0 = wrow * 32 + (ci >> 1);

    stageF(0, 0);
    loadE(0, 0);
    asm volatile("s_waitcnt vmcnt(2)" ::: "memory");
    __builtin_amdgcn_s_barrier();

#pragma unroll
    for (int ch = 0; ch < NCH; ++ch) {
        if (ch + 1 < NCH) stageF((ch + 1) & 1, ch + 1);
#pragma unroll
        for (int s = 0; s < 2; ++s) {
            int gs = ch * 2 + s;
            if (gs + 1 < 2 * NCH) loadE((gs + 1) & 1, gs + 1);
            __builtin_amdgcn_sched_barrier(0);
            int qs = (bb4 + s * 2 + g) ^ xr;
            bf16x8 fh[2], fl[2];
#pragma unroll
            for (int mi = 0; mi < 2; ++mi) {
                int off = (rpF0 + mi * 16) * 64 + qs * 8;
                fh[mi] = *reinterpret_cast<const bf16x8*>(&Fsmem[ch & 1][0][off]);
                fl[mi] = *reinterpret_cast<const bf16x8*>(&Fsmem[ch & 1][1][off]);
            }
            int cs = gs & 1;
#pragma unroll
            for (int mi = 0; mi < 2; ++mi)
#pragma unroll
                for (int ni = 0; ni < 2; ++ni) {
                    acc[mi][ni] = __builtin_amdgcn_mfma_f32_32x32x16_bf16(ehS[cs][ni], fh[mi], acc[mi][ni], 0, 0, 0);
                    acc[mi][ni] = __builtin_amdgcn_mfma_f32_32x32x16_bf16(elS[cs][ni], fh[mi], acc[mi][ni], 0, 0, 0);
                    acc[mi][ni] = __builtin_amdgcn_mfma_f32_32x32x16_bf16(ehS[cs][ni], fl[mi], acc[mi][ni], 0, 0, 0);
                }
        }
        if (ch + 1 < NCH) {
            asm volatile("s_waitcnt vmcnt(4)" ::: "memory");
            __builtin_amdgcn_s_barrier();
        }
    }

    // ---------------- epilogue (lane-local k) ----------------
    const float alpha = INV_DELTA / mdm[0];
    {
        const float* e2b = e2g + k0 + wcol * 64 + 4 * g;
#pragma unroll
        for (int ni = 0; ni < 2; ++ni)
#pragma unroll
            for (int q = 0; q < 4; ++q) {
                float4 ev = *reinterpret_cast<const float4*>(e2b + ni * 32 + 8 * q);
#pragma unroll
                for (int mi = 0; mi < 2; ++mi) {
                    acc[mi][ni][4 * q + 0] = alpha * (2.f * acc[mi][ni][4 * q + 0] - ev.x);
                    acc[mi][ni][4 * q + 1] = alpha * (2.f * acc[mi][ni][4 * q + 1] - ev.y);
                    acc[mi][ni][4 * q + 2] = alpha * (2.f * acc[mi][ni][4 * q + 2] - ev.z);
                    acc[mi][ni][4 * q + 3] = alpha * (2.f * acc[mi][ni][4 * q + 3] - ev.w);
                }
            }
    }

    float mt[2];
#pragma unroll
    for (int mi = 0; mi < 2; ++mi) {
        float m = acc[mi][0][0];
#pragma unroll
        for (int ni = 0; ni < 2; ++ni)
#pragma unroll
            for (int r = 0; r < 16; ++r) m = fmaxf(m, acc[mi][ni][r]);
        m = fmaxf(m, __shfl_xor(m, 32));
        mt[mi] = m;
        if (lane < 32) redA[wcol][wrow * 64 + mi * 32 + ci] = m;
    }
    __syncthreads();
    if (t < 128) redM[t] = fmaxf(redA[0][t], redA[1][t]);
    __syncthreads();
    float ms[2];
#pragma unroll
    for (int mi = 0; mi < 2; ++mi) ms[mi] = redM[wrow * 64 + mi * 32 + ci];

#pragma unroll
    for (int mi = 0; mi < 2; ++mi) {
        float l = 0.f;
#pragma unroll
        for (int ni = 0; ni < 2; ++ni)
#pragma unroll
            for (int r = 0; r < 16; ++r) l += exp2f((acc[mi][ni][r] - ms[mi]) * LOG2E);
        l += __shfl_xor(l, 32);
        if (lane < 32) redA[wcol][wrow * 64 + mi * 32 + ci] = l;
    }
    __syncthreads();
    if (t < 128) {
        m_part[(size_t)slab * NPIX + px0 + t] = redM[t];
        l_part[(size_t)slab * NPIX + px0 + t] = redA[0][t] + redA[1][t];
    }

#pragma unroll
    for (int mi = 0; mi < 2; ++mi) {
        int pxx = px0 + wrow * 64 + mi * 32 + ci;
        int bb = pxx / HW_, hh = pxx - bb * HW_;
        ushort* zb = zq + ((size_t)bb * K_ + (k0 + wcol * 64 + 4 * g)) * HW_ + hh;
#pragma unroll
        for (int ni = 0; ni < 2; ++ni)
#pragma unroll
            for (int q = 0; q < 4; ++q)
#pragma unroll
                for (int j = 0; j < 4; ++j) {
                    float s0 = fmaxf((acc[mi][ni][4 * q + j] - ms[mi]) * QSCALE, -32760.f);
                    short v = (short)(int)s0;
                    zb[(size_t)(ni * 32 + 8 * q + j) * HW_] = (ushort)v;
                }
    }
}

// ---------------- combine 16 slab partials ----------------
__global__ void combine_kernel(const float* __restrict__ m_part, const float* __restrict__ l_part,
                               float* __restrict__ m_fin, float* __restrict__ rl_g) {
    int p = blockIdx.x * 256 + threadIdx.x;
    float m = -3.4e38f;
#pragma unroll
    for (int s = 0; s < NSLAB; ++s) m = fmaxf(m, m_part[(size_t)s * NPIX + p]);
    float l = 0.f;
#pragma unroll
    for (int s = 0; s < NSLAB; ++s)
        l += l_part[(size_t)s * NPIX + p] * exp2f((m_part[(size_t)s * NPIX + p] - m) * LOG2E);
    m_fin[p] = m;
    rl_g[p] = 1.0f / l;
}

// ---------------- finish: 32-k blocks (2048 blocks, ~8/CU) for max TLP ----------------
__global__ __launch_bounds__(256) void finish_kernel(
    const ushort* __restrict__ zq, const float* __restrict__ m_part,
    const float* __restrict__ m_fin, const float* __restrict__ rl_g,
    float* __restrict__ codes, float* __restrict__ bow)
{
    __shared__ float corr[HW_], rls[HW_];
    __shared__ float bsum[32][4];
    int t = threadIdx.x;
    int kc = blockIdx.x, b = blockIdx.y;   // kc in [0,64): 32-k chunk
    int slab = kc >> 2;                    // 32-k chunk -> 128-k slab
    for (int i = t; i < HW_; i += 256) {
        int p = b * HW_ + i;
        corr[i] = (m_part[(size_t)slab * NPIX + p] - m_fin[p]) * LOG2E;
        rls[i] = rl_g[p];
    }
    __syncthreads();
    int wid = t >> 6, lane = t & 63;
    for (int kl = 0; kl < 32; ++kl) {
        int k = kc * 32 + kl;
        size_t base = ((size_t)b * K_ + k) * HW_;
        float ssum = 0.f;
        if (t < 196) {
            uint2 raw = *reinterpret_cast<const uint2*>(&zq[base + t * 4]);
            int q0 = (int)(short)(raw.x & 0xffffu), q1 = (int)(short)(raw.x >> 16);
            int q2 = (int)(short)(raw.y & 0xffffu), q3 = (int)(short)(raw.y >> 16);
            float4 out;
            out.x = exp2f(fmaf((float)q0, QDEC, corr[t * 4 + 0])) * rls[t * 4 + 0];
            out.y = exp2f(fmaf((float)q1, QDEC, corr[t * 4 + 1])) * rls[t * 4 + 1];
            out.z = exp2f(fmaf((float)q2, QDEC, corr[t * 4 + 2])) * rls[t * 4 + 2];
            out.w = exp2f(fmaf((float)q3, QDEC, corr[t * 4 + 3])) * rls[t * 4 + 3];
            *reinterpret_cast<float4*>(&codes[base + t * 4]) = out;
            ssum = out.x + out.y + out.z + out.w;
        }
#pragma unroll
        for (int off = 32; off > 0; off >>= 1) ssum += __shfl_xor(ssum, off);
        if (lane == 0) bsum[kl][wid] = ssum;
    }
    __syncthreads();
    if (t < 32) {
        float s = bsum[t][0] + bsum[t][1] + bsum[t][2] + bsum[t][3];
        bow[(size_t)b * K_ + kc * 32 + t] = s * (1.0f / 784.0f);
    }
}

// ---------------- bow row normalize ----------------
__global__ void bownorm_kernel(float* __restrict__ bow) {
    __shared__ float wred[4];
    __shared__ float denom_s;
    int b = blockIdx.x, t = threadIdx.x;
    float* row = bow + (size_t)b * K_;
    float v[8];
    float s = 0.f;
#pragma unroll
    for (int i = 0; i < 8; ++i) {
        v[i] = row[t + i * 256];
        s += fabsf(v[i]);
    }
#pragma unroll
    for (int off = 32; off > 0; off >>= 1) s += __shfl_xor(s, off);
    int wid = t >> 6, lane = t & 63;
    if (lane == 0) wred[wid] = s;
    __syncthreads();
    if (t == 0) denom_s = fmaxf(wred[0] + wred[1] + wred[2] + wred[3], 1e-12f);
    __syncthreads();
    float denom = denom_s;
#pragma unroll
    for (int i = 0; i < 8; ++i) row[t + i * 256] = v[i] / denom;
}

extern "C" void kernel_launch(void* const* d_in, const int* in_sizes, int n_in,
                              void* d_out, int out_size, void* d_ws, size_t ws_size,
                              hipStream_t stream) {
    const float* feat = (const float*)d_in[0];
    const float* emb  = (const float*)d_in[1];
    const float* mdm  = (const float*)d_in[2];
    float* bow   = (float*)d_out;
    float* codes = bow + (size_t)B_ * K_;

    char* ws = (char*)d_ws;
    size_t off = 0;
    auto alloc = [&](size_t bytes) { char* p = ws + off; off = (off + bytes + 255) & ~(size_t)255; return p; };
    ushort* ehi    = (ushort*)alloc((size_t)K_ * C_ * 2);
    ushort* elo    = (ushort*)alloc((size_t)K_ * C_ * 2);
    float*  e2     = (float*)alloc(K_ * 4);
    float*  m_part = (float*)alloc((size_t)NSLAB * NPIX * 4);
    float*  l_part = (float*)alloc((size_t)NSLAB * NPIX * 4);
    float*  m_fin  = (float*)alloc((size_t)NPIX * 4);
    float*  rl_g   = (float*)alloc((size_t)NPIX * 4);
    ushort* zq     = (ushort*)alloc((size_t)NPIX * K_ * 2);

    // fhi/flo live in the codes output region: dead until finish_kernel (stream-ordered).
    ushort* fhi = (ushort*)codes;
    ushort* flo = fhi + (size_t)NPIX * C_;

    prep_e_kernel<<<2048, 256, 0, stream>>>(emb, ehi, elo, e2);
    prep_f_kernel<<<392, 256, 0, stream>>>(feat, fhi, flo);
    gemm_kernel<<<3136, 256, 0, stream>>>(fhi, flo, ehi, elo, mdm, e2, zq, m_part, l_part);
    combine_kernel<<<98, 256, 0, stream>>>(m_part, l_part, m_fin, rl_g);
    finish_kernel<<<dim3(64, 32), 256, 0, stream>>>(zq, m_part, m_fin, rl_g, codes, bow);
    bownorm_kernel<<<32, 256, 0, stream>>>(bow);
}